// Round 9
// baseline (17257.886 us; speedup 1.0000x reference)
//
#include <hip/hip_runtime.h>
#include <cstddef>

// Problem constants
#define Bsz  4096
#define Sseq 16
#define Gdim 128
#define Edim 256
#define Hdim 512
#define H4   2048
#define Psteps 16
#define BK   16

typedef short bfrag8 __attribute__((ext_vector_type(8)));   // 8 bf16 (4 VGPR)
typedef float f32x4  __attribute__((ext_vector_type(4)));   // MFMA acc

// Exact 3-way bf16 split of fp32 (truncation; 24 mantissa bits = 8+8+8).
__device__ __forceinline__ void split3(float f, unsigned short& h,
                                       unsigned short& m, unsigned short& l) {
    unsigned u = __float_as_uint(f);
    h = (unsigned short)(u >> 16);
    float r1 = f - __uint_as_float(u & 0xffff0000u);
    unsigned u1 = __float_as_uint(r1);
    m = (unsigned short)(u1 >> 16);
    float r2 = r1 - __uint_as_float(u1 & 0xffff0000u);
    l = (unsigned short)(__float_as_uint(r2) >> 16);
}

// ---------------------------------------------------------------------------
// Fold kernel: gate-interleaved (row c = j*4+gate) weight prep, bf16 hi/mid/lo
// planes for the MFMA path + interleaved biases.
// ---------------------------------------------------------------------------
__global__ void fold_kernel(const float* __restrict__ encWih,
                            const float* __restrict__ encWhh,
                            const float* __restrict__ enc_b,
                            const float* __restrict__ decWih,
                            const float* __restrict__ decWhh,
                            const float* __restrict__ dec_b,
                            const float* __restrict__ embW,
                            const float* __restrict__ dec0,
                            unsigned short* __restrict__ encEh,
                            unsigned short* __restrict__ encEm,
                            unsigned short* __restrict__ encEl,
                            unsigned short* __restrict__ encWh,
                            unsigned short* __restrict__ encWm,
                            unsigned short* __restrict__ encWl,
                            unsigned short* __restrict__ decEh,
                            unsigned short* __restrict__ decEm,
                            unsigned short* __restrict__ decEl,
                            unsigned short* __restrict__ decWh,
                            unsigned short* __restrict__ decWm,
                            unsigned short* __restrict__ decWl,
                            float* __restrict__ encBI, float* __restrict__ decBI,
                            float* __restrict__ v0bI) {
    const int o = blockIdx.x;            // original row 0..2047 (gate*512 + j)
    const int gate = o >> 9, j = o & 511;
    const int c = j * 4 + gate;          // interleaved row
    const int g = threadIdx.x;           // 0..127
    float se = 0.f, sd = 0.f;
    for (int e = 0; e < Edim; ++e) {
        float w = embW[e * Gdim + g];
        se += encWih[(size_t)o * Edim + e] * w;
        sd += decWih[(size_t)o * Edim + e] * w;
    }
    unsigned short h, m, l;
    split3(se, h, m, l);
    encEh[(size_t)c * Gdim + g] = h; encEm[(size_t)c * Gdim + g] = m;
    encEl[(size_t)c * Gdim + g] = l;
    split3(sd, h, m, l);
    decEh[(size_t)c * Gdim + g] = h; decEm[(size_t)c * Gdim + g] = m;
    decEl[(size_t)c * Gdim + g] = l;
    for (int k = g; k < Hdim; k += Gdim) {
        split3(encWhh[(size_t)o * Hdim + k], h, m, l);
        encWh[(size_t)c * Hdim + k] = h; encWm[(size_t)c * Hdim + k] = m;
        encWl[(size_t)c * Hdim + k] = l;
        split3(decWhh[(size_t)o * Hdim + k], h, m, l);
        decWh[(size_t)c * Hdim + k] = h; decWm[(size_t)c * Hdim + k] = m;
        decWl[(size_t)c * Hdim + k] = l;
    }
    if (g == 0) {
        encBI[c] = enc_b[o];
        decBI[c] = dec_b[o];
        float s = dec_b[o];
        for (int e = 0; e < Edim; ++e) s += decWih[(size_t)o * Edim + e] * dec0[e];
        v0bI[c] = s;
    }
}

// ---------------------------------------------------------------------------
// MFMA gates GEMM + fused LSTM epilogue, fp32-exact via bf16x6 emulation.
// Round-9: round-7 geometry (proven best: 256 thr = 4 waves 2x2, wave tile
// 64n x 64m, grid (32,16)=512=2/CU — round 8's 32m tile raised loads/MFMA
// 0.21->0.33 and regressed) + EXPLICIT one-chunk-ahead register prefetch:
// weight frags (48 VGPR) and act fp32 (32 VGPR) for chunk ci+1 load before
// chunk ci's 96-MFMA burst, ping-ponged by parity (no indexed arrays -> no
// scratch). This overlaps the ~200-400cy L2 latency that left both pipes
// ~22% busy in round 7. 6 MFMAs/pair, order unchanged (bit-identical).
// C/D layout (m89): lane col=lane&15 -> m; the 4 regs = gates i,f,g,o of
// unit j -> lane-local epilogue. No LDS, no barriers.
// ---------------------------------------------------------------------------
__global__ __launch_bounds__(256, 2) void gates_mfma(
    const unsigned short* __restrict__ Wh1, const unsigned short* __restrict__ Wm1,
    const unsigned short* __restrict__ Wl1, int K1,
    const float* __restrict__ X, int ldx,
    const int* __restrict__ gather, int gmul,
    const unsigned short* __restrict__ Wh2, const unsigned short* __restrict__ Wm2,
    const unsigned short* __restrict__ Wl2, int K2,
    const float* __restrict__ Hin,
    const float* __restrict__ biasI,
    const float* __restrict__ c_in, float* __restrict__ h_out,
    float* __restrict__ c_out, int czero)
{
    const int tid = threadIdx.x;
    const int wv = tid >> 6, lane = tid & 63;
    const int wmi = wv & 1, wn = wv >> 1;
    const int lm = lane & 15, quad = lane >> 4;
    const int nT = blockIdx.y * 128 + wn * 64;   // output-channel tile base
    const int mB = blockIdx.x * 128 + wmi * 64;  // batch tile base

    // per-lane activation row pointers (4 m-tiles)
    int mrow[4];
    const float* xr[4];
    const float* hr[4];
#pragma unroll
    for (int tm = 0; tm < 4; ++tm) {
        int m = mB + tm * 16 + lm;
        mrow[tm] = m;
        if (X) {
            size_t off = (size_t)m * ldx;
            if (gather) off += (size_t)gather[m] * gmul;
            xr[tm] = X + off;
        }
        if (Hin) hr[tm] = Hin + (size_t)m * K2;
    }
    // per-lane weight row offsets (4 n-tiles)
    size_t aR1[4], aR2[4];
#pragma unroll
    for (int tn = 0; tn < 4; ++tn) {
        int n = nT + tn * 16 + lm;
        aR1[tn] = (size_t)n * K1;
        aR2[tn] = (size_t)n * K2;
    }

    f32x4 acc[4][4];
#pragma unroll
    for (int i = 0; i < 4; ++i)
#pragma unroll
        for (int j = 0; j < 4; ++j) acc[i][j] = (f32x4){0.f, 0.f, 0.f, 0.f};

    const int c1 = K1 >> 5;              // chunks in the x-part
    const int nc = (K1 + K2) >> 5;       // total 32-wide K chunks

    // double-buffered fragment registers (ping-pong by parity)
    bfrag8 wHa[4], wMa[4], wLa[4], wHb[4], wMb[4], wLb[4];
    float4 aA[8], aB[8];

    auto loadChunk = [&](int ci, bfrag8* fh, bfrag8* fm, bfrag8* fl, float4* fa) {
        if (ci < c1) {
            const int kk = (ci << 5) + quad * 8;
#pragma unroll
            for (int tn = 0; tn < 4; ++tn) {
                fh[tn] = *(const bfrag8*)(Wh1 + aR1[tn] + kk);
                fm[tn] = *(const bfrag8*)(Wm1 + aR1[tn] + kk);
                fl[tn] = *(const bfrag8*)(Wl1 + aR1[tn] + kk);
            }
#pragma unroll
            for (int tm = 0; tm < 4; ++tm) {
                fa[2 * tm]     = *(const float4*)(xr[tm] + kk);
                fa[2 * tm + 1] = *(const float4*)(xr[tm] + kk + 4);
            }
        } else {
            const int kk = ((ci - c1) << 5) + quad * 8;
#pragma unroll
            for (int tn = 0; tn < 4; ++tn) {
                fh[tn] = *(const bfrag8*)(Wh2 + aR2[tn] + kk);
                fm[tn] = *(const bfrag8*)(Wm2 + aR2[tn] + kk);
                fl[tn] = *(const bfrag8*)(Wl2 + aR2[tn] + kk);
            }
#pragma unroll
            for (int tm = 0; tm < 4; ++tm) {
                fa[2 * tm]     = *(const float4*)(hr[tm] + kk);
                fa[2 * tm + 1] = *(const float4*)(hr[tm] + kk + 4);
            }
        }
    };

    auto compute = [&](const bfrag8* fh, const bfrag8* fm, const bfrag8* fl,
                       const float4* fa) {
#pragma unroll
        for (int tm = 0; tm < 4; ++tm) {
            float a8[8];
            *(float4*)&a8[0] = fa[2 * tm];
            *(float4*)&a8[4] = fa[2 * tm + 1];
            bfrag8 bh, bm, bl;
#pragma unroll
            for (int j = 0; j < 8; ++j) {
                unsigned short h, m, l;
                split3(a8[j], h, m, l);
                bh[j] = (short)h; bm[j] = (short)m; bl[j] = (short)l;
            }
#pragma unroll
            for (int tn = 0; tn < 4; ++tn) {
                f32x4 c = acc[tn][tm];
                c = __builtin_amdgcn_mfma_f32_16x16x32_bf16(fh[tn], bl, c, 0, 0, 0);
                c = __builtin_amdgcn_mfma_f32_16x16x32_bf16(fl[tn], bh, c, 0, 0, 0);
                c = __builtin_amdgcn_mfma_f32_16x16x32_bf16(fm[tn], bm, c, 0, 0, 0);
                c = __builtin_amdgcn_mfma_f32_16x16x32_bf16(fh[tn], bm, c, 0, 0, 0);
                c = __builtin_amdgcn_mfma_f32_16x16x32_bf16(fm[tn], bh, c, 0, 0, 0);
                c = __builtin_amdgcn_mfma_f32_16x16x32_bf16(fh[tn], bh, c, 0, 0, 0);
                acc[tn][tm] = c;
            }
        }
    };

    loadChunk(0, wHa, wMa, wLa, aA);
    for (int ci = 0; ci < nc; ++ci) {
        if (ci & 1) {
            if (ci + 1 < nc) loadChunk(ci + 1, wHa, wMa, wLa, aA);
            compute(wHb, wMb, wLb, aB);
        } else {
            if (ci + 1 < nc) loadChunk(ci + 1, wHb, wMb, wLb, aB);
            compute(wHa, wMa, wLa, aA);
        }
    }

    // fused LSTM epilogue: lane's 4 acc regs = gates i,f,g,o of unit j
#pragma unroll
    for (int tn = 0; tn < 4; ++tn) {
        const int nb = nT + tn * 16 + quad * 4;
        float4 bb = *(const float4*)(biasI + nb);
        const int j = nb >> 2;
#pragma unroll
        for (int tm = 0; tm < 4; ++tm) {
            const size_t idx = (size_t)mrow[tm] * Hdim + j;
            float gi = acc[tn][tm][0] + bb.x;
            float gf = acc[tn][tm][1] + bb.y;
            float gg = acc[tn][tm][2] + bb.z;
            float go = acc[tn][tm][3] + bb.w;
            float si = 1.f / (1.f + expf(-gi));
            float sf = 1.f / (1.f + expf(-gf));
            float so = 1.f / (1.f + expf(-go));
            float co = czero ? 0.f : c_in[idx];
            float cn = si * tanhf(gg) + sf * co;
            c_out[idx] = cn;
            h_out[idx] = so * tanhf(cn);
        }
    }
}

// ---------------------------------------------------------------------------
// Small fp32 GEMM: C = A @ W^T + bias (4096x512, K=512). 64x64 tile, 256
// threads, 2x2 waves, per-lane 4x4 (52 VGPR, proven). Grid (8,64)=512=2/CU.
// Used for u2 (Wref2) and qp (Wq2).
// ---------------------------------------------------------------------------
__global__ __launch_bounds__(256, 4) void gemm_sm(const float* __restrict__ A,
                                                  const float* __restrict__ W,
                                                  const float* __restrict__ bias,
                                                  float* __restrict__ C, int ldc)
{
    __shared__ float As[BK][64];
    __shared__ float Bs[BK][64];
    const int tid = threadIdx.x;
    const int rowBase = blockIdx.y * 64;
    const int colBase = blockIdx.x * 64;
    const int wv = tid >> 6;
    const int waveX = wv & 1, waveY = wv >> 1;
    const int lane = tid & 63;
    const int lx = lane & 7, ly = lane >> 3;
    const int rOff = waveY * 32 + ly * 4;
    const int cOff = waveX * 32 + lx * 4;

    const int ra = tid & 63;
    const int ka = (tid >> 6) * 4;
    const float* arow = A + (size_t)(rowBase + ra) * Hdim + ka;
    const float* brow = W + (size_t)(colBase + ra) * Hdim + ka;

    float4 aR, bR;
    float acc[4][4];
#pragma unroll
    for (int i = 0; i < 4; ++i)
#pragma unroll
        for (int j = 0; j < 4; ++j) acc[i][j] = 0.f;

    aR = *(const float4*)(arow);
    bR = *(const float4*)(brow);
    for (int kt = 0; kt < Hdim; kt += BK) {
        __syncthreads();
        As[ka + 0][ra] = aR.x; As[ka + 1][ra] = aR.y;
        As[ka + 2][ra] = aR.z; As[ka + 3][ra] = aR.w;
        Bs[ka + 0][ra] = bR.x; Bs[ka + 1][ra] = bR.y;
        Bs[ka + 2][ra] = bR.z; Bs[ka + 3][ra] = bR.w;
        __syncthreads();
        if (kt + BK < Hdim) {
            aR = *(const float4*)(arow + kt + BK);
            bR = *(const float4*)(brow + kt + BK);
        }
#pragma unroll
        for (int kk = 0; kk < BK; ++kk) {
            float4 av = *(const float4*)&As[kk][rOff];
            float4 bv = *(const float4*)&Bs[kk][cOff];
            const float* ap = (const float*)&av;
            const float* bp = (const float*)&bv;
#pragma unroll
            for (int i = 0; i < 4; ++i)
#pragma unroll
                for (int j = 0; j < 4; ++j) acc[i][j] += ap[i] * bp[j];
        }
    }

    float4 bb = *(const float4*)(bias + colBase + cOff);
#pragma unroll
    for (int i = 0; i < 4; ++i) {
        const int row = rowBase + rOff + i;
        float4 o;
        o.x = acc[i][0] + bb.x;
        o.y = acc[i][1] + bb.y;
        o.z = acc[i][2] + bb.z;
        o.w = acc[i][3] + bb.w;
        *(float4*)(C + (size_t)row * ldc + colBase + cOff) = o;
    }
}

// ---------------------------------------------------------------------------
// Attention + log-softmax + argmax + state update.
// ---------------------------------------------------------------------------
__global__ __launch_bounds__(256) void attn_step(const float* __restrict__ qp,
                                                 const float* __restrict__ u2,
                                                 const float* __restrict__ Vec2,
                                                 float* __restrict__ mask,
                                                 float* __restrict__ ll_ws,
                                                 int* __restrict__ nxt,
                                                 float* __restrict__ out_map,
                                                 float* __restrict__ out_ll,
                                                 int step, int node) {
    const int b = blockIdx.x;
    __shared__ float qpS[Hdim];
    __shared__ float vS[Hdim];
    __shared__ float logitS[Sseq];
    const int tid = threadIdx.x;
    qpS[tid]       = qp[(size_t)b * Hdim + tid];
    qpS[tid + 256] = qp[(size_t)b * Hdim + 256 + tid];
    vS[tid]        = Vec2[tid];
    vS[tid + 256]  = Vec2[256 + tid];
    __syncthreads();

    const int wave = tid >> 6, lane = tid & 63;
    for (int si = 0; si < 4; ++si) {
        int s = wave * 4 + si;
        const float* u2p = u2 + ((size_t)b * Sseq + s) * Hdim;
        float sum = 0.f;
#pragma unroll
        for (int i = 0; i < 8; ++i) {
            int hh = lane + i * 64;
            sum += vS[hh] * tanhf(qpS[hh] + u2p[hh]);
        }
        for (int off = 32; off > 0; off >>= 1) sum += __shfl_down(sum, off);
        if (lane == 0) {
            float pen = step ? mask[b * Sseq + s] * 1e8f : 0.f;
            logitS[s] = 10.f * sum - pen;
        }
    }
    __syncthreads();

    if (tid == 0) {
        float mx = logitS[0];
        int am = 0;
        for (int s = 1; s < Sseq; ++s)
            if (logitS[s] > mx) { mx = logitS[s]; am = s; }
        float se = 0.f;
        for (int s = 0; s < Sseq; ++s) se += expf(logitS[s] - mx);
        float lp = -logf(se);
        float llv = (step ? ll_ws[b] : 0.f) + lp;
        ll_ws[b] = llv;
        out_ll[b] = llv;
        nxt[b] = am;
        if (step == 0) {
            for (int s = 0; s < Sseq; ++s) mask[b * Sseq + s] = (s == am) ? 1.f : 0.f;
        } else {
            mask[b * Sseq + am] += 1.f;
        }
        out_map[b * Sseq + am] = (float)node;
    }
}

// ---------------------------------------------------------------------------
extern "C" void kernel_launch(void* const* d_in, const int* in_sizes, int n_in,
                              void* d_out, int out_size, void* d_ws, size_t ws_size,
                              hipStream_t stream) {
    const float* x       = (const float*)d_in[0];
    const float* emb_W   = (const float*)d_in[1];
    const float* enc_Wih = (const float*)d_in[2];
    const float* enc_Whh = (const float*)d_in[3];
    const float* enc_b   = (const float*)d_in[4];
    const float* dec_Wih = (const float*)d_in[5];
    const float* dec_Whh = (const float*)d_in[6];
    const float* dec_b   = (const float*)d_in[7];
    const float* Wq2     = (const float*)d_in[8];
    const float* bq2     = (const float*)d_in[9];
    const float* Wref2   = (const float*)d_in[10];
    const float* bref2   = (const float*)d_in[11];
    const float* Vec2    = (const float*)d_in[12];
    const float* dec0    = (const float*)d_in[13];

    // workspace layout — ~192 MB (unchanged from round 7)
    float* ws      = (float*)d_ws;
    float* u2      = ws;                                   // B*S*H fp32
    float* h0      = u2 + (size_t)Bsz * Sseq * Hdim;       // B*H each
    float* c0      = h0 + (size_t)Bsz * Hdim;
    float* h1      = c0 + (size_t)Bsz * Hdim;
    float* c1      = h1 + (size_t)Bsz * Hdim;
    float* qp      = c1 + (size_t)Bsz * Hdim;
    float* mask    = qp + (size_t)Bsz * Hdim;              // B*S
    float* ll      = mask + (size_t)Bsz * Sseq;            // B
    int*   nxt     = (int*)(ll + Bsz);                     // B
    float* encBI   = (float*)(nxt + Bsz);                  // 2048 each
    float* decBI   = encBI + H4;
    float* v0bI    = decBI + H4;
    // bf16 weight planes (ushort)
    unsigned short* us = (unsigned short*)(v0bI + H4);
    unsigned short* encEh = us;                       us += (size_t)H4 * Gdim;
    unsigned short* encEm = us;                       us += (size_t)H4 * Gdim;
    unsigned short* encEl = us;                       us += (size_t)H4 * Gdim;
    unsigned short* encWh = us;                       us += (size_t)H4 * Hdim;
    unsigned short* encWm = us;                       us += (size_t)H4 * Hdim;
    unsigned short* encWl = us;                       us += (size_t)H4 * Hdim;
    unsigned short* decEh = us;                       us += (size_t)H4 * Gdim;
    unsigned short* decEm = us;                       us += (size_t)H4 * Gdim;
    unsigned short* decEl = us;                       us += (size_t)H4 * Gdim;
    unsigned short* decWh = us;                       us += (size_t)H4 * Hdim;
    unsigned short* decWm = us;                       us += (size_t)H4 * Hdim;
    unsigned short* decWl = us;                       us += (size_t)H4 * Hdim;

    float* out_map = (float*)d_out;                        // B*P floats
    float* out_ll  = out_map + (size_t)Bsz * Psteps;       // B floats

    static const int nodes[Psteps] = {0,0,0,0, 1,1,1,1, 2,2,2,2, 3,3,3,3};

    fold_kernel<<<H4, Gdim, 0, stream>>>(enc_Wih, enc_Whh, enc_b,
                                         dec_Wih, dec_Whh, dec_b,
                                         emb_W, dec0,
                                         encEh, encEm, encEl, encWh, encWm, encWl,
                                         decEh, decEm, decEl, decWh, decWm, decWl,
                                         encBI, decBI, v0bI);

    const dim3 gBig(32, 16);    // 512 blocks of 256 thr = 2 blocks/CU
    const dim3 gSm(8, 64);      // 512 blocks = 2/CU

    // ---- encoder: 16 fused LSTM steps + u2[t] projection of h(t) ----
    for (int t = 0; t < Sseq; ++t) {
        float* ho = (t & 1) ? h0 : h1;
        float* co = (t & 1) ? c0 : c1;
        const float* hi = (t & 1) ? h1 : h0;
        const float* ci = (t & 1) ? c1 : c0;
        if (t == 0) {
            gates_mfma<<<gBig, 256, 0, stream>>>(
                encEh, encEm, encEl, Gdim,
                x, Sseq * Gdim, nullptr, 0,
                nullptr, nullptr, nullptr, 0, nullptr,
                encBI, ci, ho, co, 1);
        } else {
            gates_mfma<<<gBig, 256, 0, stream>>>(
                encEh, encEm, encEl, Gdim,
                x + t * Gdim, Sseq * Gdim, nullptr, 0,
                encWh, encWm, encWl, Hdim, hi,
                encBI, ci, ho, co, 0);
        }
        gemm_sm<<<gSm, 256, 0, stream>>>(ho, Wref2, bref2,
                                         u2 + (size_t)t * Hdim, Sseq * Hdim);
    }

    // ---- decoder: 16 autoregressive steps ----
    for (int p = 0; p < Psteps; ++p) {
        const int u = Sseq + p;
        float* ho = (u & 1) ? h0 : h1;
        float* co = (u & 1) ? c0 : c1;
        const float* hi = (u & 1) ? h1 : h0;
        const float* ci = (u & 1) ? c1 : c0;
        if (p == 0) {
            gates_mfma<<<gBig, 256, 0, stream>>>(
                nullptr, nullptr, nullptr, 0,
                nullptr, 0, nullptr, 0,
                decWh, decWm, decWl, Hdim, hi,
                v0bI, ci, ho, co, 0);
        } else {
            gates_mfma<<<gBig, 256, 0, stream>>>(
                decEh, decEm, decEl, Gdim,
                x, Sseq * Gdim, nxt, Gdim,
                decWh, decWm, decWl, Hdim, hi,
                decBI, ci, ho, co, 0);
        }
        gemm_sm<<<gSm, 256, 0, stream>>>(ho, Wq2, bq2, qp, Hdim);
        attn_step<<<Bsz, 256, 0, stream>>>(qp, u2, Vec2, mask, ll, nxt,
                                           out_map, out_ll, p, nodes[p]);
    }
}

// Round 10
// 6811.021 us; speedup vs baseline: 2.5338x; 2.5338x over previous
//
#include <hip/hip_runtime.h>
#include <cstddef>

// Problem constants
#define Bsz  4096
#define Sseq 16
#define Gdim 128
#define Edim 256
#define Hdim 512
#define H4   2048
#define Psteps 16
#define BK   16

typedef short bfrag8 __attribute__((ext_vector_type(8)));   // 8 bf16 (4 VGPR)
typedef float f32x4  __attribute__((ext_vector_type(4)));   // MFMA acc

// Exact 3-way bf16 split of fp32 (truncation; 24 mantissa bits = 8+8+8).
__device__ __forceinline__ void split3(float f, unsigned short& h,
                                       unsigned short& m, unsigned short& l) {
    unsigned u = __float_as_uint(f);
    h = (unsigned short)(u >> 16);
    float r1 = f - __uint_as_float(u & 0xffff0000u);
    unsigned u1 = __float_as_uint(r1);
    m = (unsigned short)(u1 >> 16);
    float r2 = r1 - __uint_as_float(u1 & 0xffff0000u);
    l = (unsigned short)(__float_as_uint(r2) >> 16);
}

// ---------------------------------------------------------------------------
// Fold kernel: gate-interleaved (row c = j*4+gate) weight prep, bf16 hi/mid/lo
// planes for the MFMA path + interleaved biases.
// ---------------------------------------------------------------------------
__global__ void fold_kernel(const float* __restrict__ encWih,
                            const float* __restrict__ encWhh,
                            const float* __restrict__ enc_b,
                            const float* __restrict__ decWih,
                            const float* __restrict__ decWhh,
                            const float* __restrict__ dec_b,
                            const float* __restrict__ embW,
                            const float* __restrict__ dec0,
                            unsigned short* __restrict__ encEh,
                            unsigned short* __restrict__ encEm,
                            unsigned short* __restrict__ encEl,
                            unsigned short* __restrict__ encWh,
                            unsigned short* __restrict__ encWm,
                            unsigned short* __restrict__ encWl,
                            unsigned short* __restrict__ decEh,
                            unsigned short* __restrict__ decEm,
                            unsigned short* __restrict__ decEl,
                            unsigned short* __restrict__ decWh,
                            unsigned short* __restrict__ decWm,
                            unsigned short* __restrict__ decWl,
                            float* __restrict__ encBI, float* __restrict__ decBI,
                            float* __restrict__ v0bI) {
    const int o = blockIdx.x;            // original row 0..2047 (gate*512 + j)
    const int gate = o >> 9, j = o & 511;
    const int c = j * 4 + gate;          // interleaved row
    const int g = threadIdx.x;           // 0..127
    float se = 0.f, sd = 0.f;
    for (int e = 0; e < Edim; ++e) {
        float w = embW[e * Gdim + g];
        se += encWih[(size_t)o * Edim + e] * w;
        sd += decWih[(size_t)o * Edim + e] * w;
    }
    unsigned short h, m, l;
    split3(se, h, m, l);
    encEh[(size_t)c * Gdim + g] = h; encEm[(size_t)c * Gdim + g] = m;
    encEl[(size_t)c * Gdim + g] = l;
    split3(sd, h, m, l);
    decEh[(size_t)c * Gdim + g] = h; decEm[(size_t)c * Gdim + g] = m;
    decEl[(size_t)c * Gdim + g] = l;
    for (int k = g; k < Hdim; k += Gdim) {
        split3(encWhh[(size_t)o * Hdim + k], h, m, l);
        encWh[(size_t)c * Hdim + k] = h; encWm[(size_t)c * Hdim + k] = m;
        encWl[(size_t)c * Hdim + k] = l;
        split3(decWhh[(size_t)o * Hdim + k], h, m, l);
        decWh[(size_t)c * Hdim + k] = h; decWm[(size_t)c * Hdim + k] = m;
        decWl[(size_t)c * Hdim + k] = l;
    }
    if (g == 0) {
        encBI[c] = enc_b[o];
        decBI[c] = dec_b[o];
        float s = dec_b[o];
        for (int e = 0; e < Edim; ++e) s += decWih[(size_t)o * Edim + e] * dec0[e];
        v0bI[c] = s;
    }
}

// ---------------------------------------------------------------------------
// MFMA gates GEMM + fused LSTM epilogue, fp32-exact via bf16x6 emulation.
// Round-10: round-7 geometry (best proven: 256 thr = 4 waves 2x2, wave tile
// 64n x 64m, grid (32,16)=512=2/CU) + 2-deep register pipeline written as
// MACRO-EXPANDED named buffers (wH0/wH1/.., aV0/aV1) indexed ONLY by
// #pragma-unrolled induction vars. Round 9's lambda-pointer version defeated
// SROA -> 1.6 GB scratch spill; round 4's 16x8 tile spilled the same way.
// Budget: 64 acc + 48+32 buf0 + 48+32 buf1 + ~25 addr ~ 176 VGPR < 256 cap.
// Chunk counts are always even (4/16/20) -> clean 2-stage pipeline.
// 6 MFMAs/pair (hh+hm+mh+mm+hl+lh, order fixed) -> bit-identical to r7.
// C/D layout (m89): lane col=lane&15 -> m; 4 regs = gates i,f,g,o of unit j.
// ---------------------------------------------------------------------------
__global__ __launch_bounds__(256, 2) void gates_mfma(
    const unsigned short* __restrict__ Wh1, const unsigned short* __restrict__ Wm1,
    const unsigned short* __restrict__ Wl1, int K1,
    const float* __restrict__ X, int ldx,
    const int* __restrict__ gather, int gmul,
    const unsigned short* __restrict__ Wh2, const unsigned short* __restrict__ Wm2,
    const unsigned short* __restrict__ Wl2, int K2,
    const float* __restrict__ Hin,
    const float* __restrict__ biasI,
    const float* __restrict__ c_in, float* __restrict__ h_out,
    float* __restrict__ c_out, int czero)
{
    const int tid = threadIdx.x;
    const int wv = tid >> 6, lane = tid & 63;
    const int wmi = wv & 1, wn = wv >> 1;
    const int lm = lane & 15, quad = lane >> 4;
    const int q8 = quad * 8;
    const int nT = blockIdx.y * 128 + wn * 64;   // output-channel tile base
    const int mB = blockIdx.x * 128 + wmi * 64;  // batch tile base

    // per-lane activation row pointers (4 m-tiles)
    int mrow[4];
    const float* xr[4];
    const float* hr[4];
#pragma unroll
    for (int tm = 0; tm < 4; ++tm) {
        int m = mB + tm * 16 + lm;
        mrow[tm] = m;
        if (X) {
            size_t off = (size_t)m * ldx;
            if (gather) off += (size_t)gather[m] * gmul;
            xr[tm] = X + off;
        } else xr[tm] = nullptr;
        hr[tm] = Hin ? (Hin + (size_t)m * K2) : nullptr;
    }
    // per-lane weight row offsets (4 n-tiles)
    size_t aR1[4], aR2[4];
#pragma unroll
    for (int tn = 0; tn < 4; ++tn) {
        int n = nT + tn * 16 + lm;
        aR1[tn] = (size_t)n * K1;
        aR2[tn] = (size_t)n * K2;
    }

    f32x4 acc[4][4];
#pragma unroll
    for (int i = 0; i < 4; ++i)
#pragma unroll
        for (int j = 0; j < 4; ++j) acc[i][j] = (f32x4){0.f, 0.f, 0.f, 0.f};

    const int c1 = K1 >> 5;              // chunks in the x-part
    const int nc = (K1 + K2) >> 5;       // total 32-wide K chunks (even)

    // double-buffered fragment registers: plain named locals, constant-indexed
    bfrag8 wH0[4], wM0[4], wL0[4], wH1[4], wM1[4], wL1[4];
    float4 aV0[8], aV1[8];

#define LOADC(B, ci_)                                                        \
    {                                                                        \
        if ((ci_) < c1) {                                                    \
            const int kk_ = ((ci_) << 5) + q8;                               \
            _Pragma("unroll")                                                \
            for (int tn = 0; tn < 4; ++tn) {                                 \
                wH##B[tn] = *(const bfrag8*)(Wh1 + aR1[tn] + kk_);           \
                wM##B[tn] = *(const bfrag8*)(Wm1 + aR1[tn] + kk_);           \
                wL##B[tn] = *(const bfrag8*)(Wl1 + aR1[tn] + kk_);           \
            }                                                                \
            _Pragma("unroll")                                                \
            for (int tm = 0; tm < 4; ++tm) {                                 \
                aV##B[2 * tm]     = *(const float4*)(xr[tm] + kk_);          \
                aV##B[2 * tm + 1] = *(const float4*)(xr[tm] + kk_ + 4);      \
            }                                                                \
        } else {                                                             \
            const int kk_ = (((ci_) - c1) << 5) + q8;                        \
            _Pragma("unroll")                                                \
            for (int tn = 0; tn < 4; ++tn) {                                 \
                wH##B[tn] = *(const bfrag8*)(Wh2 + aR2[tn] + kk_);           \
                wM##B[tn] = *(const bfrag8*)(Wm2 + aR2[tn] + kk_);           \
                wL##B[tn] = *(const bfrag8*)(Wl2 + aR2[tn] + kk_);           \
            }                                                                \
            _Pragma("unroll")                                                \
            for (int tm = 0; tm < 4; ++tm) {                                 \
                aV##B[2 * tm]     = *(const float4*)(hr[tm] + kk_);          \
                aV##B[2 * tm + 1] = *(const float4*)(hr[tm] + kk_ + 4);      \
            }                                                                \
        }                                                                    \
    }

#define COMPC(B)                                                             \
    {                                                                        \
        _Pragma("unroll")                                                    \
        for (int tm = 0; tm < 4; ++tm) {                                     \
            float a8_[8];                                                    \
            *(float4*)&a8_[0] = aV##B[2 * tm];                               \
            *(float4*)&a8_[4] = aV##B[2 * tm + 1];                           \
            bfrag8 bh_, bm_, bl_;                                            \
            _Pragma("unroll")                                                \
            for (int j = 0; j < 8; ++j) {                                    \
                unsigned short h_, m_, l_;                                   \
                split3(a8_[j], h_, m_, l_);                                  \
                bh_[j] = (short)h_; bm_[j] = (short)m_; bl_[j] = (short)l_;  \
            }                                                                \
            _Pragma("unroll")                                                \
            for (int tn = 0; tn < 4; ++tn) {                                 \
                f32x4 c_ = acc[tn][tm];                                      \
                c_ = __builtin_amdgcn_mfma_f32_16x16x32_bf16(wH##B[tn], bl_, c_, 0, 0, 0); \
                c_ = __builtin_amdgcn_mfma_f32_16x16x32_bf16(wL##B[tn], bh_, c_, 0, 0, 0); \
                c_ = __builtin_amdgcn_mfma_f32_16x16x32_bf16(wM##B[tn], bm_, c_, 0, 0, 0); \
                c_ = __builtin_amdgcn_mfma_f32_16x16x32_bf16(wH##B[tn], bm_, c_, 0, 0, 0); \
                c_ = __builtin_amdgcn_mfma_f32_16x16x32_bf16(wM##B[tn], bh_, c_, 0, 0, 0); \
                c_ = __builtin_amdgcn_mfma_f32_16x16x32_bf16(wH##B[tn], bh_, c_, 0, 0, 0); \
                acc[tn][tm] = c_;                                            \
            }                                                                \
        }                                                                    \
    }

    LOADC(0, 0);
    for (int ci = 0; ci < nc; ci += 2) {
        LOADC(1, ci + 1);
        COMPC(0);
        if (ci + 2 < nc) LOADC(0, ci + 2);
        COMPC(1);
    }
#undef LOADC
#undef COMPC

    // fused LSTM epilogue: lane's 4 acc regs = gates i,f,g,o of unit j
#pragma unroll
    for (int tn = 0; tn < 4; ++tn) {
        const int nb = nT + tn * 16 + quad * 4;
        float4 bb = *(const float4*)(biasI + nb);
        const int j = nb >> 2;
#pragma unroll
        for (int tm = 0; tm < 4; ++tm) {
            const size_t idx = (size_t)mrow[tm] * Hdim + j;
            float gi = acc[tn][tm][0] + bb.x;
            float gf = acc[tn][tm][1] + bb.y;
            float gg = acc[tn][tm][2] + bb.z;
            float go = acc[tn][tm][3] + bb.w;
            float si = 1.f / (1.f + expf(-gi));
            float sf = 1.f / (1.f + expf(-gf));
            float so = 1.f / (1.f + expf(-go));
            float co = czero ? 0.f : c_in[idx];
            float cn = si * tanhf(gg) + sf * co;
            c_out[idx] = cn;
            h_out[idx] = so * tanhf(cn);
        }
    }
}

// ---------------------------------------------------------------------------
// Small fp32 GEMM: C = A @ W^T + bias (4096x512, K=512). 64x64 tile, 256
// threads, 2x2 waves, per-lane 4x4 (52 VGPR, proven). Grid (8,64)=512=2/CU.
// Used for u2 (Wref2) and qp (Wq2).
// ---------------------------------------------------------------------------
__global__ __launch_bounds__(256, 4) void gemm_sm(const float* __restrict__ A,
                                                  const float* __restrict__ W,
                                                  const float* __restrict__ bias,
                                                  float* __restrict__ C, int ldc)
{
    __shared__ float As[BK][64];
    __shared__ float Bs[BK][64];
    const int tid = threadIdx.x;
    const int rowBase = blockIdx.y * 64;
    const int colBase = blockIdx.x * 64;
    const int wv = tid >> 6;
    const int waveX = wv & 1, waveY = wv >> 1;
    const int lane = tid & 63;
    const int lx = lane & 7, ly = lane >> 3;
    const int rOff = waveY * 32 + ly * 4;
    const int cOff = waveX * 32 + lx * 4;

    const int ra = tid & 63;
    const int ka = (tid >> 6) * 4;
    const float* arow = A + (size_t)(rowBase + ra) * Hdim + ka;
    const float* brow = W + (size_t)(colBase + ra) * Hdim + ka;

    float4 aR, bR;
    float acc[4][4];
#pragma unroll
    for (int i = 0; i < 4; ++i)
#pragma unroll
        for (int j = 0; j < 4; ++j) acc[i][j] = 0.f;

    aR = *(const float4*)(arow);
    bR = *(const float4*)(brow);
    for (int kt = 0; kt < Hdim; kt += BK) {
        __syncthreads();
        As[ka + 0][ra] = aR.x; As[ka + 1][ra] = aR.y;
        As[ka + 2][ra] = aR.z; As[ka + 3][ra] = aR.w;
        Bs[ka + 0][ra] = bR.x; Bs[ka + 1][ra] = bR.y;
        Bs[ka + 2][ra] = bR.z; Bs[ka + 3][ra] = bR.w;
        __syncthreads();
        if (kt + BK < Hdim) {
            aR = *(const float4*)(arow + kt + BK);
            bR = *(const float4*)(brow + kt + BK);
        }
#pragma unroll
        for (int kk = 0; kk < BK; ++kk) {
            float4 av = *(const float4*)&As[kk][rOff];
            float4 bv = *(const float4*)&Bs[kk][cOff];
            const float* ap = (const float*)&av;
            const float* bp = (const float*)&bv;
#pragma unroll
            for (int i = 0; i < 4; ++i)
#pragma unroll
                for (int j = 0; j < 4; ++j) acc[i][j] += ap[i] * bp[j];
        }
    }

    float4 bb = *(const float4*)(bias + colBase + cOff);
#pragma unroll
    for (int i = 0; i < 4; ++i) {
        const int row = rowBase + rOff + i;
        float4 o;
        o.x = acc[i][0] + bb.x;
        o.y = acc[i][1] + bb.y;
        o.z = acc[i][2] + bb.z;
        o.w = acc[i][3] + bb.w;
        *(float4*)(C + (size_t)row * ldc + colBase + cOff) = o;
    }
}

// ---------------------------------------------------------------------------
// Attention + log-softmax + argmax + state update.
// ---------------------------------------------------------------------------
__global__ __launch_bounds__(256) void attn_step(const float* __restrict__ qp,
                                                 const float* __restrict__ u2,
                                                 const float* __restrict__ Vec2,
                                                 float* __restrict__ mask,
                                                 float* __restrict__ ll_ws,
                                                 int* __restrict__ nxt,
                                                 float* __restrict__ out_map,
                                                 float* __restrict__ out_ll,
                                                 int step, int node) {
    const int b = blockIdx.x;
    __shared__ float qpS[Hdim];
    __shared__ float vS[Hdim];
    __shared__ float logitS[Sseq];
    const int tid = threadIdx.x;
    qpS[tid]       = qp[(size_t)b * Hdim + tid];
    qpS[tid + 256] = qp[(size_t)b * Hdim + 256 + tid];
    vS[tid]        = Vec2[tid];
    vS[tid + 256]  = Vec2[256 + tid];
    __syncthreads();

    const int wave = tid >> 6, lane = tid & 63;
    for (int si = 0; si < 4; ++si) {
        int s = wave * 4 + si;
        const float* u2p = u2 + ((size_t)b * Sseq + s) * Hdim;
        float sum = 0.f;
#pragma unroll
        for (int i = 0; i < 8; ++i) {
            int hh = lane + i * 64;
            sum += vS[hh] * tanhf(qpS[hh] + u2p[hh]);
        }
        for (int off = 32; off > 0; off >>= 1) sum += __shfl_down(sum, off);
        if (lane == 0) {
            float pen = step ? mask[b * Sseq + s] * 1e8f : 0.f;
            logitS[s] = 10.f * sum - pen;
        }
    }
    __syncthreads();

    if (tid == 0) {
        float mx = logitS[0];
        int am = 0;
        for (int s = 1; s < Sseq; ++s)
            if (logitS[s] > mx) { mx = logitS[s]; am = s; }
        float se = 0.f;
        for (int s = 0; s < Sseq; ++s) se += expf(logitS[s] - mx);
        float lp = -logf(se);
        float llv = (step ? ll_ws[b] : 0.f) + lp;
        ll_ws[b] = llv;
        out_ll[b] = llv;
        nxt[b] = am;
        if (step == 0) {
            for (int s = 0; s < Sseq; ++s) mask[b * Sseq + s] = (s == am) ? 1.f : 0.f;
        } else {
            mask[b * Sseq + am] += 1.f;
        }
        out_map[b * Sseq + am] = (float)node;
    }
}

// ---------------------------------------------------------------------------
extern "C" void kernel_launch(void* const* d_in, const int* in_sizes, int n_in,
                              void* d_out, int out_size, void* d_ws, size_t ws_size,
                              hipStream_t stream) {
    const float* x       = (const float*)d_in[0];
    const float* emb_W   = (const float*)d_in[1];
    const float* enc_Wih = (const float*)d_in[2];
    const float* enc_Whh = (const float*)d_in[3];
    const float* enc_b   = (const float*)d_in[4];
    const float* dec_Wih = (const float*)d_in[5];
    const float* dec_Whh = (const float*)d_in[6];
    const float* dec_b   = (const float*)d_in[7];
    const float* Wq2     = (const float*)d_in[8];
    const float* bq2     = (const float*)d_in[9];
    const float* Wref2   = (const float*)d_in[10];
    const float* bref2   = (const float*)d_in[11];
    const float* Vec2    = (const float*)d_in[12];
    const float* dec0    = (const float*)d_in[13];

    // workspace layout — ~192 MB (unchanged from round 7)
    float* ws      = (float*)d_ws;
    float* u2      = ws;                                   // B*S*H fp32
    float* h0      = u2 + (size_t)Bsz * Sseq * Hdim;       // B*H each
    float* c0      = h0 + (size_t)Bsz * Hdim;
    float* h1      = c0 + (size_t)Bsz * Hdim;
    float* c1      = h1 + (size_t)Bsz * Hdim;
    float* qp      = c1 + (size_t)Bsz * Hdim;
    float* mask    = qp + (size_t)Bsz * Hdim;              // B*S
    float* ll      = mask + (size_t)Bsz * Sseq;            // B
    int*   nxt     = (int*)(ll + Bsz);                     // B
    float* encBI   = (float*)(nxt + Bsz);                  // 2048 each
    float* decBI   = encBI + H4;
    float* v0bI    = decBI + H4;
    // bf16 weight planes (ushort)
    unsigned short* us = (unsigned short*)(v0bI + H4);
    unsigned short* encEh = us;                       us += (size_t)H4 * Gdim;
    unsigned short* encEm = us;                       us += (size_t)H4 * Gdim;
    unsigned short* encEl = us;                       us += (size_t)H4 * Gdim;
    unsigned short* encWh = us;                       us += (size_t)H4 * Hdim;
    unsigned short* encWm = us;                       us += (size_t)H4 * Hdim;
    unsigned short* encWl = us;                       us += (size_t)H4 * Hdim;
    unsigned short* decEh = us;                       us += (size_t)H4 * Gdim;
    unsigned short* decEm = us;                       us += (size_t)H4 * Gdim;
    unsigned short* decEl = us;                       us += (size_t)H4 * Gdim;
    unsigned short* decWh = us;                       us += (size_t)H4 * Hdim;
    unsigned short* decWm = us;                       us += (size_t)H4 * Hdim;
    unsigned short* decWl = us;                       us += (size_t)H4 * Hdim;

    float* out_map = (float*)d_out;                        // B*P floats
    float* out_ll  = out_map + (size_t)Bsz * Psteps;       // B floats

    static const int nodes[Psteps] = {0,0,0,0, 1,1,1,1, 2,2,2,2, 3,3,3,3};

    fold_kernel<<<H4, Gdim, 0, stream>>>(enc_Wih, enc_Whh, enc_b,
                                         dec_Wih, dec_Whh, dec_b,
                                         emb_W, dec0,
                                         encEh, encEm, encEl, encWh, encWm, encWl,
                                         decEh, decEm, decEl, decWh, decWm, decWl,
                                         encBI, decBI, v0bI);

    const dim3 gBig(32, 16);    // 512 blocks of 256 thr = 2 blocks/CU
    const dim3 gSm(8, 64);      // 512 blocks = 2/CU

    // ---- encoder: 16 fused LSTM steps + u2[t] projection of h(t) ----
    for (int t = 0; t < Sseq; ++t) {
        float* ho = (t & 1) ? h0 : h1;
        float* co = (t & 1) ? c0 : c1;
        const float* hi = (t & 1) ? h1 : h0;
        const float* ci = (t & 1) ? c1 : c0;
        if (t == 0) {
            gates_mfma<<<gBig, 256, 0, stream>>>(
                encEh, encEm, encEl, Gdim,
                x, Sseq * Gdim, nullptr, 0,
                nullptr, nullptr, nullptr, 0, nullptr,
                encBI, ci, ho, co, 1);
        } else {
            gates_mfma<<<gBig, 256, 0, stream>>>(
                encEh, encEm, encEl, Gdim,
                x + t * Gdim, Sseq * Gdim, nullptr, 0,
                encWh, encWm, encWl, Hdim, hi,
                encBI, ci, ho, co, 0);
        }
        gemm_sm<<<gSm, 256, 0, stream>>>(ho, Wref2, bref2,
                                         u2 + (size_t)t * Hdim, Sseq * Hdim);
    }

    // ---- decoder: 16 autoregressive steps ----
    for (int p = 0; p < Psteps; ++p) {
        const int u = Sseq + p;
        float* ho = (u & 1) ? h0 : h1;
        float* co = (u & 1) ? c0 : c1;
        const float* hi = (u & 1) ? h1 : h0;
        const float* ci = (u & 1) ? c1 : c0;
        if (p == 0) {
            gates_mfma<<<gBig, 256, 0, stream>>>(
                nullptr, nullptr, nullptr, 0,
                nullptr, 0, nullptr, 0,
                decWh, decWm, decWl, Hdim, hi,
                v0bI, ci, ho, co, 0);
        } else {
            gates_mfma<<<gBig, 256, 0, stream>>>(
                decEh, decEm, decEl, Gdim,
                x, Sseq * Gdim, nxt, Gdim,
                decWh, decWm, decWl, Hdim, hi,
                decBI, ci, ho, co, 0);
        }
        gemm_sm<<<gSm, 256, 0, stream>>>(ho, Wq2, bq2, qp, Hdim);
        attn_step<<<Bsz, 256, 0, stream>>>(qp, u2, Vec2, mask, ll, nxt,
                                           out_map, out_ll, p, nodes[p]);
    }
}

// Round 11
// 5331.096 us; speedup vs baseline: 3.2372x; 1.2776x over previous
//
#include <hip/hip_runtime.h>
#include <cstddef>

// Problem constants
#define Bsz  4096
#define Sseq 16
#define Gdim 128
#define Edim 256
#define Hdim 512
#define H4   2048
#define Psteps 16

typedef short bfrag8 __attribute__((ext_vector_type(8)));   // 8 bf16 (4 VGPR)
typedef float f32x4  __attribute__((ext_vector_type(4)));   // MFMA acc

// Exact 3-way bf16 split of fp32 (truncation; 24 mantissa bits = 8+8+8).
__device__ __forceinline__ void split3(float f, unsigned short& h,
                                       unsigned short& m, unsigned short& l) {
    unsigned u = __float_as_uint(f);
    h = (unsigned short)(u >> 16);
    float r1 = f - __uint_as_float(u & 0xffff0000u);
    unsigned u1 = __float_as_uint(r1);
    m = (unsigned short)(u1 >> 16);
    float r2 = r1 - __uint_as_float(u1 & 0xffff0000u);
    l = (unsigned short)(__float_as_uint(r2) >> 16);
}

// ---------------------------------------------------------------------------
// Fold kernel: gate-interleaved (row c = j*4+gate) LSTM weight prep (bf16
// hi/mid/lo planes) + interleaved biases + NEW: Wref2/Wq2 plane splits for
// the MFMA small-GEMM path (rows 0..511 handle one Wref2/Wq2 row each).
// ---------------------------------------------------------------------------
__global__ void fold_kernel(const float* __restrict__ encWih,
                            const float* __restrict__ encWhh,
                            const float* __restrict__ enc_b,
                            const float* __restrict__ decWih,
                            const float* __restrict__ decWhh,
                            const float* __restrict__ dec_b,
                            const float* __restrict__ embW,
                            const float* __restrict__ dec0,
                            const float* __restrict__ Wref2,
                            const float* __restrict__ Wq2,
                            unsigned short* __restrict__ encEh,
                            unsigned short* __restrict__ encEm,
                            unsigned short* __restrict__ encEl,
                            unsigned short* __restrict__ encWh,
                            unsigned short* __restrict__ encWm,
                            unsigned short* __restrict__ encWl,
                            unsigned short* __restrict__ decEh,
                            unsigned short* __restrict__ decEm,
                            unsigned short* __restrict__ decEl,
                            unsigned short* __restrict__ decWh,
                            unsigned short* __restrict__ decWm,
                            unsigned short* __restrict__ decWl,
                            unsigned short* __restrict__ refH,
                            unsigned short* __restrict__ refM,
                            unsigned short* __restrict__ refL,
                            unsigned short* __restrict__ qH,
                            unsigned short* __restrict__ qM,
                            unsigned short* __restrict__ qL,
                            float* __restrict__ encBI, float* __restrict__ decBI,
                            float* __restrict__ v0bI) {
    const int o = blockIdx.x;            // original row 0..2047 (gate*512 + j)
    const int gate = o >> 9, j = o & 511;
    const int c = j * 4 + gate;          // interleaved row
    const int g = threadIdx.x;           // 0..127
    float se = 0.f, sd = 0.f;
    for (int e = 0; e < Edim; ++e) {
        float w = embW[e * Gdim + g];
        se += encWih[(size_t)o * Edim + e] * w;
        sd += decWih[(size_t)o * Edim + e] * w;
    }
    unsigned short h, m, l;
    split3(se, h, m, l);
    encEh[(size_t)c * Gdim + g] = h; encEm[(size_t)c * Gdim + g] = m;
    encEl[(size_t)c * Gdim + g] = l;
    split3(sd, h, m, l);
    decEh[(size_t)c * Gdim + g] = h; decEm[(size_t)c * Gdim + g] = m;
    decEl[(size_t)c * Gdim + g] = l;
    for (int k = g; k < Hdim; k += Gdim) {
        split3(encWhh[(size_t)o * Hdim + k], h, m, l);
        encWh[(size_t)c * Hdim + k] = h; encWm[(size_t)c * Hdim + k] = m;
        encWl[(size_t)c * Hdim + k] = l;
        split3(decWhh[(size_t)o * Hdim + k], h, m, l);
        decWh[(size_t)c * Hdim + k] = h; decWm[(size_t)c * Hdim + k] = m;
        decWl[(size_t)c * Hdim + k] = l;
    }
    if (o < Hdim) {
        for (int k = g; k < Hdim; k += Gdim) {
            split3(Wref2[(size_t)o * Hdim + k], h, m, l);
            refH[(size_t)o * Hdim + k] = h; refM[(size_t)o * Hdim + k] = m;
            refL[(size_t)o * Hdim + k] = l;
            split3(Wq2[(size_t)o * Hdim + k], h, m, l);
            qH[(size_t)o * Hdim + k] = h; qM[(size_t)o * Hdim + k] = m;
            qL[(size_t)o * Hdim + k] = l;
        }
    }
    if (g == 0) {
        encBI[c] = enc_b[o];
        decBI[c] = dec_b[o];
        float s = dec_b[o];
        for (int e = 0; e < Edim; ++e) s += decWih[(size_t)o * Edim + e] * dec0[e];
        v0bI[c] = s;
    }
}

// ---------------------------------------------------------------------------
// MFMA gates GEMM + fused LSTM epilogue, fp32-exact via bf16x6 emulation.
// EXACT round-7 kernel (121 us proven; 96 VGPR, no spill). Three attempts at
// register double-buffering (r4/r9/r10) all hit the compiler's hard 128-VGPR
// allocation wall and spilled to scratch — do NOT add prefetch state here.
// 256 thr = 4 waves 2x2, wave tile 64n x 64m, grid (32,16)=512=2/CU.
// 6 MFMAs/pair: hh+hm+mh+mm+hl+lh; dropped terms ~2^-24.
// C/D layout (m89): lane col=lane&15 -> m (batch row); the 4 regs = gates
// i,f,g,o of unit j (gate-interleaved cols) -> lane-local epilogue. No LDS.
// ---------------------------------------------------------------------------
__global__ __launch_bounds__(256) void gates_mfma(
    const unsigned short* __restrict__ Wh1, const unsigned short* __restrict__ Wm1,
    const unsigned short* __restrict__ Wl1, int K1,
    const float* __restrict__ X, int ldx,
    const int* __restrict__ gather, int gmul,
    const unsigned short* __restrict__ Wh2, const unsigned short* __restrict__ Wm2,
    const unsigned short* __restrict__ Wl2, int K2,
    const float* __restrict__ Hin,
    const float* __restrict__ biasI,
    const float* __restrict__ c_in, float* __restrict__ h_out,
    float* __restrict__ c_out, int czero)
{
    const int tid = threadIdx.x;
    const int wv = tid >> 6, lane = tid & 63;
    const int wm = wv & 1, wn = wv >> 1;
    const int lm = lane & 15, quad = lane >> 4;
    const int nT = blockIdx.y * 128 + wn * 64;   // output-channel tile base
    const int mB = blockIdx.x * 128 + wm * 64;   // batch tile base

    // per-lane activation row pointers (4 m-tiles)
    int mrow[4];
    const float* xr[4];
    const float* hr[4];
#pragma unroll
    for (int tm = 0; tm < 4; ++tm) {
        int m = mB + tm * 16 + lm;
        mrow[tm] = m;
        if (X) {
            size_t off = (size_t)m * ldx;
            if (gather) off += (size_t)gather[m] * gmul;
            xr[tm] = X + off;
        }
        if (Hin) hr[tm] = Hin + (size_t)m * K2;
    }
    // per-lane weight row offsets (4 n-tiles)
    size_t aR1[4], aR2[4];
#pragma unroll
    for (int tn = 0; tn < 4; ++tn) {
        int n = nT + tn * 16 + lm;
        aR1[tn] = (size_t)n * K1;
        aR2[tn] = (size_t)n * K2;
    }

    f32x4 acc[4][4];
#pragma unroll
    for (int i = 0; i < 4; ++i)
#pragma unroll
        for (int j = 0; j < 4; ++j) acc[i][j] = (f32x4){0.f, 0.f, 0.f, 0.f};

    const int KT = K1 + K2;
    for (int kc = 0; kc < KT; kc += 32) {
        const bool inX = kc < K1;
        const int kk = (inX ? kc : kc - K1) + quad * 8;

        bfrag8 ah[4], am[4], al[4];
#pragma unroll
        for (int tn = 0; tn < 4; ++tn) {
            if (inX) {
                ah[tn] = *(const bfrag8*)(Wh1 + aR1[tn] + kk);
                am[tn] = *(const bfrag8*)(Wm1 + aR1[tn] + kk);
                al[tn] = *(const bfrag8*)(Wl1 + aR1[tn] + kk);
            } else {
                ah[tn] = *(const bfrag8*)(Wh2 + aR2[tn] + kk);
                am[tn] = *(const bfrag8*)(Wm2 + aR2[tn] + kk);
                al[tn] = *(const bfrag8*)(Wl2 + aR2[tn] + kk);
            }
        }
#pragma unroll
        for (int tm = 0; tm < 4; ++tm) {
            const float* p = (inX ? xr[tm] : hr[tm]) + kk;
            float a8[8];
            *(float4*)&a8[0] = *(const float4*)(p);
            *(float4*)&a8[4] = *(const float4*)(p + 4);
            bfrag8 bh, bm, bl;
#pragma unroll
            for (int j = 0; j < 8; ++j) {
                unsigned short h, m, l;
                split3(a8[j], h, m, l);
                bh[j] = (short)h; bm[j] = (short)m; bl[j] = (short)l;
            }
#pragma unroll
            for (int tn = 0; tn < 4; ++tn) {
                f32x4 c = acc[tn][tm];
                c = __builtin_amdgcn_mfma_f32_16x16x32_bf16(ah[tn], bl, c, 0, 0, 0);
                c = __builtin_amdgcn_mfma_f32_16x16x32_bf16(al[tn], bh, c, 0, 0, 0);
                c = __builtin_amdgcn_mfma_f32_16x16x32_bf16(am[tn], bm, c, 0, 0, 0);
                c = __builtin_amdgcn_mfma_f32_16x16x32_bf16(ah[tn], bm, c, 0, 0, 0);
                c = __builtin_amdgcn_mfma_f32_16x16x32_bf16(am[tn], bh, c, 0, 0, 0);
                c = __builtin_amdgcn_mfma_f32_16x16x32_bf16(ah[tn], bh, c, 0, 0, 0);
                acc[tn][tm] = c;
            }
        }
    }

    // fused LSTM epilogue: lane's 4 acc regs = gates i,f,g,o of unit j
#pragma unroll
    for (int tn = 0; tn < 4; ++tn) {
        const int nb = nT + tn * 16 + quad * 4;
        float4 bb = *(const float4*)(biasI + nb);
        const int j = nb >> 2;
#pragma unroll
        for (int tm = 0; tm < 4; ++tm) {
            const size_t idx = (size_t)mrow[tm] * Hdim + j;
            float gi = acc[tn][tm][0] + bb.x;
            float gf = acc[tn][tm][1] + bb.y;
            float gg = acc[tn][tm][2] + bb.z;
            float go = acc[tn][tm][3] + bb.w;
            float si = 1.f / (1.f + expf(-gi));
            float sf = 1.f / (1.f + expf(-gf));
            float so = 1.f / (1.f + expf(-go));
            float co = czero ? 0.f : c_in[idx];
            float cn = si * tanhf(gg) + sf * co;
            c_out[idx] = cn;
            h_out[idx] = so * tanhf(cn);
        }
    }
}

// ---------------------------------------------------------------------------
// MFMA small GEMM (bf16x6, same emulation as gates): C[m][n] = sum_k
// W[n][k]*A[m][k] + bias[n], for the u2 (Wref2) and qp (Wq2) projections.
// 512n x 4096m, K=512. Wave tile 32n x 32m (acc only 16 VGPR — far from the
// 128-VGPR spill wall); 4 waves 2x2 -> block 64n x 64m; grid (64,8)=512=2/CU.
// Branch-free 16-chunk K loop. Epilogue: lane's 4 regs = 4 consecutive n of
// one batch row m -> single float4 store at C[m*ldc + n]. No LDS.
// ---------------------------------------------------------------------------
__global__ __launch_bounds__(256) void mfma_sm(
    const unsigned short* __restrict__ Wh, const unsigned short* __restrict__ Wm,
    const unsigned short* __restrict__ Wl,
    const float* __restrict__ A,
    const float* __restrict__ bias,
    float* __restrict__ C, int ldc)
{
    const int tid = threadIdx.x;
    const int wv = tid >> 6, lane = tid & 63;
    const int wmi = wv & 1, wn = wv >> 1;
    const int lm = lane & 15, quad = lane >> 4;
    const int nT = blockIdx.y * 64 + wn * 32;
    const int mB = blockIdx.x * 64 + wmi * 32;

    int mrow[2];
    const float* ar[2];
#pragma unroll
    for (int tm = 0; tm < 2; ++tm) {
        int m = mB + tm * 16 + lm;
        mrow[tm] = m;
        ar[tm] = A + (size_t)m * Hdim;
    }
    size_t wr[2];
#pragma unroll
    for (int tn = 0; tn < 2; ++tn)
        wr[tn] = (size_t)(nT + tn * 16 + lm) * Hdim;

    f32x4 acc[2][2];
#pragma unroll
    for (int i = 0; i < 2; ++i)
#pragma unroll
        for (int j = 0; j < 2; ++j) acc[i][j] = (f32x4){0.f, 0.f, 0.f, 0.f};

    for (int kc = 0; kc < Hdim; kc += 32) {
        const int kk = kc + quad * 8;
        bfrag8 ah[2], am[2], al[2];
#pragma unroll
        for (int tn = 0; tn < 2; ++tn) {
            ah[tn] = *(const bfrag8*)(Wh + wr[tn] + kk);
            am[tn] = *(const bfrag8*)(Wm + wr[tn] + kk);
            al[tn] = *(const bfrag8*)(Wl + wr[tn] + kk);
        }
#pragma unroll
        for (int tm = 0; tm < 2; ++tm) {
            float a8[8];
            *(float4*)&a8[0] = *(const float4*)(ar[tm] + kk);
            *(float4*)&a8[4] = *(const float4*)(ar[tm] + kk + 4);
            bfrag8 bh, bm, bl;
#pragma unroll
            for (int j = 0; j < 8; ++j) {
                unsigned short h, m, l;
                split3(a8[j], h, m, l);
                bh[j] = (short)h; bm[j] = (short)m; bl[j] = (short)l;
            }
#pragma unroll
            for (int tn = 0; tn < 2; ++tn) {
                f32x4 c = acc[tn][tm];
                c = __builtin_amdgcn_mfma_f32_16x16x32_bf16(ah[tn], bl, c, 0, 0, 0);
                c = __builtin_amdgcn_mfma_f32_16x16x32_bf16(al[tn], bh, c, 0, 0, 0);
                c = __builtin_amdgcn_mfma_f32_16x16x32_bf16(am[tn], bm, c, 0, 0, 0);
                c = __builtin_amdgcn_mfma_f32_16x16x32_bf16(ah[tn], bm, c, 0, 0, 0);
                c = __builtin_amdgcn_mfma_f32_16x16x32_bf16(am[tn], bh, c, 0, 0, 0);
                c = __builtin_amdgcn_mfma_f32_16x16x32_bf16(ah[tn], bh, c, 0, 0, 0);
                acc[tn][tm] = c;
            }
        }
    }

#pragma unroll
    for (int tn = 0; tn < 2; ++tn) {
        const int nb = nT + tn * 16 + quad * 4;
        float4 bb = *(const float4*)(bias + nb);
#pragma unroll
        for (int tm = 0; tm < 2; ++tm) {
            float4 o;
            o.x = acc[tn][tm][0] + bb.x;
            o.y = acc[tn][tm][1] + bb.y;
            o.z = acc[tn][tm][2] + bb.z;
            o.w = acc[tn][tm][3] + bb.w;
            *(float4*)(C + (size_t)mrow[tm] * ldc + nb) = o;
        }
    }
}

// ---------------------------------------------------------------------------
// Attention + log-softmax + argmax + state update.
// ---------------------------------------------------------------------------
__global__ __launch_bounds__(256) void attn_step(const float* __restrict__ qp,
                                                 const float* __restrict__ u2,
                                                 const float* __restrict__ Vec2,
                                                 float* __restrict__ mask,
                                                 float* __restrict__ ll_ws,
                                                 int* __restrict__ nxt,
                                                 float* __restrict__ out_map,
                                                 float* __restrict__ out_ll,
                                                 int step, int node) {
    const int b = blockIdx.x;
    __shared__ float qpS[Hdim];
    __shared__ float vS[Hdim];
    __shared__ float logitS[Sseq];
    const int tid = threadIdx.x;
    qpS[tid]       = qp[(size_t)b * Hdim + tid];
    qpS[tid + 256] = qp[(size_t)b * Hdim + 256 + tid];
    vS[tid]        = Vec2[tid];
    vS[tid + 256]  = Vec2[256 + tid];
    __syncthreads();

    const int wave = tid >> 6, lane = tid & 63;
    for (int si = 0; si < 4; ++si) {
        int s = wave * 4 + si;
        const float* u2p = u2 + ((size_t)b * Sseq + s) * Hdim;
        float sum = 0.f;
#pragma unroll
        for (int i = 0; i < 8; ++i) {
            int hh = lane + i * 64;
            sum += vS[hh] * tanhf(qpS[hh] + u2p[hh]);
        }
        for (int off = 32; off > 0; off >>= 1) sum += __shfl_down(sum, off);
        if (lane == 0) {
            float pen = step ? mask[b * Sseq + s] * 1e8f : 0.f;
            logitS[s] = 10.f * sum - pen;
        }
    }
    __syncthreads();

    if (tid == 0) {
        float mx = logitS[0];
        int am = 0;
        for (int s = 1; s < Sseq; ++s)
            if (logitS[s] > mx) { mx = logitS[s]; am = s; }
        float se = 0.f;
        for (int s = 0; s < Sseq; ++s) se += expf(logitS[s] - mx);
        float lp = -logf(se);
        float llv = (step ? ll_ws[b] : 0.f) + lp;
        ll_ws[b] = llv;
        out_ll[b] = llv;
        nxt[b] = am;
        if (step == 0) {
            for (int s = 0; s < Sseq; ++s) mask[b * Sseq + s] = (s == am) ? 1.f : 0.f;
        } else {
            mask[b * Sseq + am] += 1.f;
        }
        out_map[b * Sseq + am] = (float)node;
    }
}

// ---------------------------------------------------------------------------
extern "C" void kernel_launch(void* const* d_in, const int* in_sizes, int n_in,
                              void* d_out, int out_size, void* d_ws, size_t ws_size,
                              hipStream_t stream) {
    const float* x       = (const float*)d_in[0];
    const float* emb_W   = (const float*)d_in[1];
    const float* enc_Wih = (const float*)d_in[2];
    const float* enc_Whh = (const float*)d_in[3];
    const float* enc_b   = (const float*)d_in[4];
    const float* dec_Wih = (const float*)d_in[5];
    const float* dec_Whh = (const float*)d_in[6];
    const float* dec_b   = (const float*)d_in[7];
    const float* Wq2     = (const float*)d_in[8];
    const float* bq2     = (const float*)d_in[9];
    const float* Wref2   = (const float*)d_in[10];
    const float* bref2   = (const float*)d_in[11];
    const float* Vec2    = (const float*)d_in[12];
    const float* dec0    = (const float*)d_in[13];

    // workspace layout — ~196 MB
    float* ws      = (float*)d_ws;
    float* u2      = ws;                                   // B*S*H fp32
    float* h0      = u2 + (size_t)Bsz * Sseq * Hdim;       // B*H each
    float* c0      = h0 + (size_t)Bsz * Hdim;
    float* h1      = c0 + (size_t)Bsz * Hdim;
    float* c1      = h1 + (size_t)Bsz * Hdim;
    float* qp      = c1 + (size_t)Bsz * Hdim;
    float* mask    = qp + (size_t)Bsz * Hdim;              // B*S
    float* ll      = mask + (size_t)Bsz * Sseq;            // B
    int*   nxt     = (int*)(ll + Bsz);                     // B
    float* encBI   = (float*)(nxt + Bsz);                  // 2048 each
    float* decBI   = encBI + H4;
    float* v0bI    = decBI + H4;
    // bf16 weight planes (ushort)
    unsigned short* us = (unsigned short*)(v0bI + H4);
    unsigned short* encEh = us;                       us += (size_t)H4 * Gdim;
    unsigned short* encEm = us;                       us += (size_t)H4 * Gdim;
    unsigned short* encEl = us;                       us += (size_t)H4 * Gdim;
    unsigned short* encWh = us;                       us += (size_t)H4 * Hdim;
    unsigned short* encWm = us;                       us += (size_t)H4 * Hdim;
    unsigned short* encWl = us;                       us += (size_t)H4 * Hdim;
    unsigned short* decEh = us;                       us += (size_t)H4 * Gdim;
    unsigned short* decEm = us;                       us += (size_t)H4 * Gdim;
    unsigned short* decEl = us;                       us += (size_t)H4 * Gdim;
    unsigned short* decWh = us;                       us += (size_t)H4 * Hdim;
    unsigned short* decWm = us;                       us += (size_t)H4 * Hdim;
    unsigned short* decWl = us;                       us += (size_t)H4 * Hdim;
    unsigned short* refH  = us;                       us += (size_t)Hdim * Hdim;
    unsigned short* refM  = us;                       us += (size_t)Hdim * Hdim;
    unsigned short* refL  = us;                       us += (size_t)Hdim * Hdim;
    unsigned short* qH    = us;                       us += (size_t)Hdim * Hdim;
    unsigned short* qM    = us;                       us += (size_t)Hdim * Hdim;
    unsigned short* qL    = us;                       us += (size_t)Hdim * Hdim;

    float* out_map = (float*)d_out;                        // B*P floats
    float* out_ll  = out_map + (size_t)Bsz * Psteps;       // B floats

    static const int nodes[Psteps] = {0,0,0,0, 1,1,1,1, 2,2,2,2, 3,3,3,3};

    fold_kernel<<<H4, Gdim, 0, stream>>>(enc_Wih, enc_Whh, enc_b,
                                         dec_Wih, dec_Whh, dec_b,
                                         emb_W, dec0, Wref2, Wq2,
                                         encEh, encEm, encEl, encWh, encWm, encWl,
                                         decEh, decEm, decEl, decWh, decWm, decWl,
                                         refH, refM, refL, qH, qM, qL,
                                         encBI, decBI, v0bI);

    const dim3 gBig(32, 16);    // 512 blocks of 256 thr = 2 blocks/CU
    const dim3 gSm(64, 8);      // 512 blocks of 256 thr = 2 blocks/CU

    // ---- encoder: 16 fused LSTM steps + u2[t] projection of h(t) ----
    for (int t = 0; t < Sseq; ++t) {
        float* ho = (t & 1) ? h0 : h1;
        float* co = (t & 1) ? c0 : c1;
        const float* hi = (t & 1) ? h1 : h0;
        const float* ci = (t & 1) ? c1 : c0;
        if (t == 0) {
            gates_mfma<<<gBig, 256, 0, stream>>>(
                encEh, encEm, encEl, Gdim,
                x, Sseq * Gdim, nullptr, 0,
                nullptr, nullptr, nullptr, 0, nullptr,
                encBI, ci, ho, co, 1);
        } else {
            gates_mfma<<<gBig, 256, 0, stream>>>(
                encEh, encEm, encEl, Gdim,
                x + t * Gdim, Sseq * Gdim, nullptr, 0,
                encWh, encWm, encWl, Hdim, hi,
                encBI, ci, ho, co, 0);
        }
        mfma_sm<<<gSm, 256, 0, stream>>>(refH, refM, refL, ho, bref2,
                                         u2 + (size_t)t * Hdim, Sseq * Hdim);
    }

    // ---- decoder: 16 autoregressive steps ----
    for (int p = 0; p < Psteps; ++p) {
        const int u = Sseq + p;
        float* ho = (u & 1) ? h0 : h1;
        float* co = (u & 1) ? c0 : c1;
        const float* hi = (u & 1) ? h1 : h0;
        const float* ci = (u & 1) ? c1 : c0;
        if (p == 0) {
            gates_mfma<<<gBig, 256, 0, stream>>>(
                nullptr, nullptr, nullptr, 0,
                nullptr, 0, nullptr, 0,
                decWh, decWm, decWl, Hdim, hi,
                v0bI, ci, ho, co, 0);
        } else {
            gates_mfma<<<gBig, 256, 0, stream>>>(
                decEh, decEm, decEl, Gdim,
                x, Sseq * Gdim, nxt, Gdim,
                decWh, decWm, decWl, Hdim, hi,
                decBI, ci, ho, co, 0);
        }
        mfma_sm<<<gSm, 256, 0, stream>>>(qH, qM, qL, ho, bq2, qp, Hdim);
        attn_step<<<Bsz, 256, 0, stream>>>(qp, u2, Vec2, mask, ll, nxt,
                                           out_map, out_ll, p, nodes[p]);
    }
}